// Round 1
// baseline (236.100 us; speedup 1.0000x reference)
//
#include <hip/hip_runtime.h>

// Problem constants (from reference): N=1024 turns, L=64, D=1024.
// Output [N, L, 2D] float32: first half = questions, second half = prefix mean.
constexpr int N_TURNS = 1024;
constexpr int L_LEN   = 64;
constexpr int D_MOD   = 1024;
constexpr int COLS    = L_LEN * D_MOD;     // 65536 independent scan columns
constexpr int C4      = COLS / 4;          // 16384 float4 columns (2^14)
constexpr int NCHUNK  = 16;                // chunks along the turn axis
constexpr int CHUNK_S = N_TURNS / NCHUNK;  // 64 rows per chunk

__device__ __forceinline__ float4 f4_add(float4 a, float4 b) {
    return make_float4(a.x + b.x, a.y + b.y, a.z + b.z, a.w + b.w);
}

// Pass 1: partial[c][col4] = sum over rows in chunk c of q[row][col4]
__global__ __launch_bounds__(256) void chunk_sum_kernel(
        const float4* __restrict__ q, float4* __restrict__ partial) {
    int t   = blockIdx.x * blockDim.x + threadIdx.x;  // [0, NCHUNK*C4)
    int c   = t >> 14;            // chunk index
    int col = t & (C4 - 1);       // float4 column, fast-varying -> coalesced
    float4 sum = make_float4(0.f, 0.f, 0.f, 0.f);
    int base = c * CHUNK_S;
    #pragma unroll 4
    for (int j = 0; j < CHUNK_S; ++j) {
        sum = f4_add(sum, q[(size_t)(base + j) * C4 + col]);
    }
    partial[(size_t)c * C4 + col] = sum;
}

// Pass 2: each thread owns (chunk c, float4 column). Accumulate exclusive
// prefix of chunk sums, then scan the chunk's rows emitting both halves.
__global__ __launch_bounds__(256) void emit_kernel(
        const float4* __restrict__ q, const float4* __restrict__ partial,
        float4* __restrict__ out) {
    int t   = blockIdx.x * blockDim.x + threadIdx.x;
    int c   = t >> 14;
    int col = t & (C4 - 1);

    float4 run = make_float4(0.f, 0.f, 0.f, 0.f);
    for (int cc = 0; cc < c; ++cc) {
        run = f4_add(run, partial[(size_t)cc * C4 + col]);
    }

    // col -> (l, d/4): d-index within row for output addressing
    int dcol = col & (D_MOD / 4 - 1);      // float4 index within d
    // row base in out (float4 units): row has 2*D floats = 512 float4
    constexpr int ROW_F4 = 2 * D_MOD / 4;  // 512
    constexpr int HALF_F4 = D_MOD / 4;     // 256

    int base = c * CHUNK_S;
    for (int j = 0; j < CHUNK_S; ++j) {
        int i = base + j;
        float4 v = q[(size_t)i * C4 + col];
        float inv = (i == 0) ? 0.0f : (1.0f / (float)i);
        float4 a = make_float4(run.x * inv, run.y * inv, run.z * inv, run.w * inv);
        // out row index = i*L + l; col = l*(D/4) + dcol so i*C4+col expands to:
        size_t ob = (size_t)i * (size_t)ROW_F4 * L_LEN
                  + (size_t)(col >> 8) * ROW_F4;   // l * ROW_F4
        out[ob + dcol] = v;
        out[ob + HALF_F4 + dcol] = a;
        run = f4_add(run, v);
    }
}

// Fallback (ws too small): one thread per float4 column, serial over N.
__global__ __launch_bounds__(256) void single_pass_kernel(
        const float4* __restrict__ q, float4* __restrict__ out) {
    int col = blockIdx.x * blockDim.x + threadIdx.x;  // [0, C4)
    if (col >= C4) return;
    constexpr int ROW_F4 = 2 * D_MOD / 4;
    constexpr int HALF_F4 = D_MOD / 4;
    float4 run = make_float4(0.f, 0.f, 0.f, 0.f);
    int dcol = col & (D_MOD / 4 - 1);
    for (int i = 0; i < N_TURNS; ++i) {
        float4 v = q[(size_t)i * C4 + col];
        float inv = (i == 0) ? 0.0f : (1.0f / (float)i);
        float4 a = make_float4(run.x * inv, run.y * inv, run.z * inv, run.w * inv);
        size_t ob = (size_t)i * (size_t)ROW_F4 * L_LEN
                  + (size_t)(col >> 8) * ROW_F4;
        out[ob + dcol] = v;
        out[ob + HALF_F4 + dcol] = a;
        run = f4_add(run, v);
    }
}

extern "C" void kernel_launch(void* const* d_in, const int* in_sizes, int n_in,
                              void* d_out, int out_size, void* d_ws, size_t ws_size,
                              hipStream_t stream) {
    const float4* q = (const float4*)d_in[0];
    float4* out = (float4*)d_out;

    const size_t ws_needed = (size_t)NCHUNK * COLS * sizeof(float);  // 4 MiB
    if (ws_size >= ws_needed) {
        float4* partial = (float4*)d_ws;
        int total = NCHUNK * C4;                 // 262144 threads
        chunk_sum_kernel<<<total / 256, 256, 0, stream>>>(q, partial);
        emit_kernel<<<total / 256, 256, 0, stream>>>(q, partial, out);
    } else {
        single_pass_kernel<<<(C4 + 255) / 256, 256, 0, stream>>>(q, out);
    }
}

// Round 2
// 153.580 us; speedup vs baseline: 1.5373x; 1.5373x over previous
//
#include <hip/hip_runtime.h>

// QuestionFlowLayer: out[i] = concat(q[i], mean(q[0:i]))  for q [1024, 64, 1024] f32.
// Single-pass minimal-traffic kernel: one thread per scalar column (65536 columns),
// serial scan over the 1024 turns. Reads input once (256 MiB), writes output once
// (512 MiB). Wave lanes map to consecutive columns -> fully coalesced 256B
// transactions for the load and both store halves.
constexpr int N_TURNS = 1024;
constexpr int L_LEN   = 64;
constexpr int D_MOD   = 1024;
constexpr unsigned COLS = L_LEN * D_MOD;           // 65536 scalar columns
constexpr unsigned ROW_STRIDE_OUT = 2u * D_MOD * L_LEN; // floats per turn in out: 131072

__global__ __launch_bounds__(256) void qflow_scan_kernel(
        const float* __restrict__ q, float* __restrict__ out) {
    unsigned c = blockIdx.x * 256u + threadIdx.x;   // column index [0, 65536)
    unsigned l = c >> 10;                           // which L row
    unsigned d = c & (D_MOD - 1);                   // which d element

    const float* qp = q + c;                        // q[i][c] = qp[i * COLS]
    float* op = out + (size_t)l * (2u * D_MOD) + d; // out[i][l][d]    = op[i*ROW_STRIDE_OUT]
                                                    // out[i][l][D+d]  = op[i*ROW_STRIDE_OUT + D]
    float run = 0.0f;
    #pragma unroll 32
    for (unsigned i = 0; i < N_TURNS; ++i) {
        float v = qp[(size_t)i * COLS];
        // inv = 1/i (0 for i==0). i is wave-uniform; rcp is 1 VALU instr,
        // rel err ~1e-7 << threshold margin.
        float inv = (i == 0) ? 0.0f : __builtin_amdgcn_rcpf((float)i);
        float avg = run * inv;
        size_t ob = (size_t)i * ROW_STRIDE_OUT;
        op[ob] = v;
        op[ob + D_MOD] = avg;
        run += v;
    }
}

extern "C" void kernel_launch(void* const* d_in, const int* in_sizes, int n_in,
                              void* d_out, int out_size, void* d_ws, size_t ws_size,
                              hipStream_t stream) {
    const float* q = (const float*)d_in[0];
    float* out = (float*)d_out;
    qflow_scan_kernel<<<COLS / 256, 256, 0, stream>>>(q, out);
}